// Round 14
// baseline (318.991 us; speedup 1.0000x reference)
//
#include <hip/hip_runtime.h>

// GC-LSTM (SMPL) — fp32 I/O. Round 21: round 20 (303.9 us; main 229) + projection
// fused as a TAIL into main (not interleaved — that was round 16's failure;
// this uses proj's proven coalesced LDS staging, once, after the s-loop).
// Each block projects its own 2 samples: A = 48 rows x 576 seqh (L1/L2-warm,
// b128 row-chunks), B = WdH (L2-resident), 6 K-chunks x {stage, BAR, 15 MFMA,
// BAR}, C -> out. LDS overlay on dead PQt/UO (26,624 <= 26,880 B).
// Deletes the 1536-block proj launch. Fallback (!preconv) keeps old proj.

typedef short  s16x8 __attribute__((ext_vector_type(8)));
typedef float  f32x4 __attribute__((ext_vector_type(4)));
typedef _Float16 f16x8 __attribute__((ext_vector_type(8)));

#define TPB 192
#define NB 2
#define PQ_OFF 0        // ushort[96][104] = 19,968 : PQt[n][j'] f16
#define UO_OFF 19968    // ushort[48][72]  =  6,912 : k=2d X | 2d+1 h (d<24), 48-63 zero
#define SMEM_SZ 26880

#define BAR() do { asm volatile("s_waitcnt lgkmcnt(0)" ::: "memory"); \
                   __builtin_amdgcn_s_barrier(); } while (0)

#define L2E  1.4426950408889634f
#define L2E2 2.8853900817779268f

__device__ __forceinline__ unsigned short f2h(float f) {
    _Float16 h = (_Float16)f;            // RNE scalar convert (init paths)
    return *(unsigned short*)&h;
}
// hardware packed f32x2 -> f16x2 (RTZ), low = a, high = b : 1 VALU inst
__device__ __forceinline__ unsigned int pkrtz(float a, float b) {
    auto h = __builtin_amdgcn_cvt_pkrtz(a, b);   // __fp16 ext_vector_type(2)
    return *(unsigned int*)&h;
}
__device__ __forceinline__ float frcp(float x) { return __builtin_amdgcn_rcpf(x); }

#if __has_builtin(__builtin_amdgcn_exp2f)
#define EXP2(x) __builtin_amdgcn_exp2f(x)
#else
#define EXP2(x) __expf((x) * 0.6931471805599453f)
#endif

// sigmoid with PRE-SCALED argument y = log2e * x : 1/(1+2^-y)
__device__ __forceinline__ float sigm2(float y) {
    float t = EXP2(-y);
    return frcp(1.0f + t);
}
// tanh with PRE-SCALED argument ys = 2*log2e * x : (1-2^-ys)/(1+2^-ys)
__device__ __forceinline__ float tanh2s(float ys) {
    float t = EXP2(fminf(-ys, 86.64f));
    return (1.f - t) * frcp(1.f + t);
}
// tanh of a TRUE-scale value (cell state)
__device__ __forceinline__ float tanhc(float x) {
    float t = EXP2(fminf(x * -L2E2, 86.64f));
    return (1.f - t) * frcp(1.f + t);
}

// lane^8 exchange (within 16-lane rows) — DPP row_ror:8 if available
#if __has_builtin(__builtin_amdgcn_mov_dpp)
__device__ __forceinline__ float xor8(float v) {
    int r = __builtin_amdgcn_mov_dpp(__float_as_int(v), 0x128, 0xf, 0xf, false);
    return __int_as_float(r);
}
#else
__device__ __forceinline__ float xor8(float v) { return __shfl_xor(v, 8); }
#endif

template <int FUSE>
__global__ void __launch_bounds__(TPB, 3)
gclstm_main(const float* __restrict__ src,
            const float* __restrict__ tgt,
            const float* __restrict__ We,
            const float* __restrict__ be,
            const float* __restrict__ Wxl,
            const float* __restrict__ bxl,
            const float* __restrict__ Wxr,
            const float* __restrict__ Whl,
            const float* __restrict__ bhl,
            const float* __restrict__ Whr,
            const float* __restrict__ wg,
            const float* __restrict__ bg,
            unsigned short* __restrict__ seqh,
            const unsigned short* __restrict__ WdH,
            const float* __restrict__ bd,
            float* __restrict__ out)
{
    __shared__ __align__(16) char smem[SMEM_SZ];
    unsigned short* PQt  = (unsigned short*)(smem + PQ_OFF);
    unsigned short* UO   = (unsigned short*)(smem + UO_OFF);
    unsigned int*   UO32 = (unsigned int*)(smem + UO_OFF);

    const int tid = threadIdx.x;
    const int b0 = blockIdx.x * NB;
    const int lane = tid & 63, wid = tid >> 6;      // 3 waves
    const int l15 = lane & 15, quad = lane >> 4;

    const int par[24] = {-1,0,0,0,1,2,3,4,5,6,7,8,9,9,9,12,13,14,16,17,18,19,20,21};

    // ---- stage-1 weight fragments in registers: wave wid owns col-tiles 4w..4w+3
    // k interleaved: k=2d -> X-feature d (Wx), k=2d+1 -> h-feature d (Wh); k>=48 zero
    f16x8 w1f[4][2];
#pragma unroll
    for (int cj = 0; cj < 4; ++cj) {
        int np = (wid * 4 + cj) * 16 + l15;
        int path = np >= 96 ? 1 : 0;
        int nn = np - path * 96;
        int g = nn / 24, d = nn - g * 24;
        const float* Wx = path ? Wxr : Wxl;
        const float* Wh = path ? Whr : Whl;
#pragma unroll
        for (int kt = 0; kt < 2; ++kt) {
            f16x8 f;
#pragma unroll
            for (int kk = 0; kk < 8; ++kk) {
                int k = kt * 32 + quad * 8 + kk;
                float v = 0.f;
                if (k < 48) {
                    int df = k >> 1;
                    v = (k & 1) ? Wh[g * 576 + d * 24 + df] : Wx[g * 576 + d * 24 + df];
                }
                f[kk] = (_Float16)v;
            }
            w1f[cj][kt] = f;
        }
    }

    // ---- M' fragments: wave owns rows wid*16..+15. Sample-major j' layout:
    //      j' = sample*48 + path*24 + j ; path0 adjacency (0/1), path1 diag cnt.
    f16x8 mf[3];
    {
        int i = wid * 16 + l15;
        int si = i / 24, ji = i - si * 24;
        int cnt = 1 + (par[ji] >= 0 ? 1 : 0);
#pragma unroll
        for (int ch = 0; ch < 24; ++ch) cnt += (par[ch] == ji) ? 1 : 0;
        float cntf = (float)cnt;
#pragma unroll
        for (int kt = 0; kt < 3; ++kt) {
            f16x8 f;
#pragma unroll
            for (int kk = 0; kk < 8; ++kk) {
                int jp = kt * 32 + quad * 8 + kk;
                int sj = jp / 48;
                int rem = jp - sj * 48;
                int pz = rem / 24;
                int j = rem - pz * 24;
                float v = 0.f;
                if (sj == si) {
                    if (pz == 0) v = (j == ji || par[j] == ji || par[ji] == j) ? 1.f : 0.f;
                    else         v = (j == ji) ? cntf : 0.f;
                }
                f[kk] = (_Float16)v;
            }
            mf[kt] = f;
        }
    }

    // ---- per-lane gate constants: d1 = l15, d2 = 16+(l15&7)
    // PRE-SCALED: i/f/o-gate consts x log2e (sigm2); c-gate consts x 2*log2e (tanh2s)
    const int d1 = l15;
    const int d2 = 16 + (l15 & 7);
    const bool lo = l15 < 8;
    float bC1[4], bC2[4], wv1[3], wv2[3];
#pragma unroll
    for (int g = 0; g < 4; ++g) {
        float sc = (g == 2) ? L2E2 : L2E;
        bC1[g] = (bxl[g * 24 + d1] + bhl[g * 24 + d1] + bg[g * 24 + d1]) * sc;
        bC2[g] = (bxl[g * 24 + d2] + bhl[g * 24 + d2] + bg[g * 24 + d2]) * sc;
    }
#pragma unroll
    for (int p = 0; p < 3; ++p) {
        wv1[p] = wg[p * 24 + d1] * L2E;
        wv2[p] = wg[p * 24 + d2] * L2E;
    }

    int rowR[4];
    float iwR1[4], iwR2[4];
    unsigned int sb[4];
#pragma unroll
    for (int rr = 0; rr < 4; ++rr) {
        int row = wid * 16 + quad * 4 + rr;
        rowR[rr] = row;
        int j = row % 24;
        int cnt = 1 + (par[j] >= 0 ? 1 : 0);
#pragma unroll
        for (int ch = 0; ch < 24; ++ch) cnt += (par[ch] == j) ? 1 : 0;
        float iw = cnt == 2 ? 0.5f : cnt == 3 ? (1.f / 3.f) : cnt == 4 ? 0.25f : 0.2f;
        iwR1[rr] = iw * L2E;
        iwR2[rr] = iw * L2E2;
        sb[rr] = (unsigned int)((b0 + row / 24) * 13824 + j * 24);
    }
    // d2 element constants (element e active on rr = lo ? e : e+2)
    int row2v[2]; float iw2v1[2], iw2v2[2]; unsigned int sb2v[2];
#pragma unroll
    for (int e = 0; e < 2; ++e) {
        int rsel = lo ? e : e + 2;
        row2v[e] = rowR[rsel];
        iw2v1[e] = iwR1[rsel]; iw2v2[e] = iwR2[rsel];
        sb2v[e] = sb[rsel];
    }

    float c1[4] = {0.f, 0.f, 0.f, 0.f};
    float c2[2] = {0.f, 0.f};

    // ---- encoder init: X at even k, h=0 at odd k; pad k 48..63 zeroed ----
#pragma unroll
    for (int t = 0; t < 3; ++t) {
        int task = tid + t * TPB;
        int row = task / 12, dp = task - row * 12;
        int b = b0 + row / 24, j = row % 24;
        const float* sp = src + (size_t)b * 1728 + j * 3;
        float s0 = sp[0], s1 = sp[1], s2 = sp[2];
        int d = 2 * dp;
        float x0 = be[d] + s0 * We[d * 3] + s1 * We[d * 3 + 1] + s2 * We[d * 3 + 2];
        float x1 = be[d + 1] + s0 * We[d * 3 + 3] + s1 * We[d * 3 + 4] + s2 * We[d * 3 + 5];
        x0 = fmaxf(x0, 0.f); x1 = fmaxf(x1, 0.f);
        uint2 wv; wv.x = pkrtz(x0, 0.f); wv.y = pkrtz(x1, 0.f);
        *(uint2*)(UO32 + row * 36 + 2 * dp) = wv;   // shorts [x0,0,x1,0]
    }
    {   // zero pad k=48..63 for all 48 rows (192 threads x 1 uint2 exactly)
        int row = tid >> 2, c = tid & 3;
        uint2 z; z.x = 0u; z.y = 0u;
        *(uint2*)(UO32 + row * 36 + 24 + 2 * c) = z;
    }
    __syncthreads();

    for (int s = 0; s < 48; ++s) {
        if (s == 24) {
            // decode inject: X = relu(enc(tgt[:,0])) at even k only; h preserved
#pragma unroll
            for (int t = 0; t < 3; ++t) {
                int task = tid + t * TPB;
                int row = task / 12, dp = task - row * 12;
                int b = b0 + row / 24, j = row % 24;
                const float* tp = tgt + (size_t)b * 1728 + j * 3;
                float s0 = tp[0], s1 = tp[1], s2 = tp[2];
                int d = 2 * dp;
                float x0 = be[d] + s0 * We[d * 3] + s1 * We[d * 3 + 1] + s2 * We[d * 3 + 2];
                float x1 = be[d + 1] + s0 * We[d * 3 + 3] + s1 * We[d * 3 + 4]
                         + s2 * We[d * 3 + 5];
                x0 = fmaxf(x0, 0.f); x1 = fmaxf(x1, 0.f);
                UO[row * 72 + 4 * dp] = f2h(x0);
                UO[row * 72 + 4 * dp + 2] = f2h(x1);
            }
            BAR();
        }

        // ---- phase 1: stage-1 MFMA (read UO) + pack -> PQt ----
        f32x4 acc1[3][4];
#pragma unroll
        for (int rt = 0; rt < 3; ++rt)
#pragma unroll
            for (int cj = 0; cj < 4; ++cj) acc1[rt][cj] = (f32x4)0.f;
        __builtin_amdgcn_s_setprio(1);
#pragma unroll
        for (int kt = 0; kt < 2; ++kt) {
            f16x8 a[3];
#pragma unroll
            for (int rt = 0; rt < 3; ++rt)
                a[rt] = *(const f16x8*)(UO + (rt * 16 + l15) * 72 + kt * 32 + quad * 8);
#pragma unroll
            for (int rt = 0; rt < 3; ++rt)
#pragma unroll
                for (int cj = 0; cj < 4; ++cj)
                    acc1[rt][cj] = __builtin_amdgcn_mfma_f32_16x16x32_f16(a[rt], w1f[cj][kt], acc1[rt][cj], 0, 0, 0);
        }
        __builtin_amdgcn_s_setprio(0);
#pragma unroll
        for (int rt = 0; rt < 3; ++rt)
#pragma unroll
            for (int cj = 0; cj < 4; ++cj) {
                int np = (wid * 4 + cj) * 16 + l15;
                int path = np >= 96;
                int nn = np - (path ? 96 : 0);
                int jg = rt * 16 + quad * 4;
                int col = (path ? 24 : 0) + jg + (jg >= 24 ? 24 : 0);
                uint2 wv;
                wv.x = pkrtz(acc1[rt][cj][0], acc1[rt][cj][1]);
                wv.y = pkrtz(acc1[rt][cj][2], acc1[rt][cj][3]);
                *(uint2*)(PQt + nn * 104 + col) = wv;
            }
        BAR();   // (A) PQt ready; UO reads done

        // ---- phase 2: stage-2 MFMA, row-tile ownership; sample-skip kt ----
        f32x4 acc2[6];
#pragma unroll
        for (int nt = 0; nt < 6; ++nt) acc2[nt] = (f32x4)0.f;
        __builtin_amdgcn_s_setprio(1);
#pragma unroll
        for (int kt = 0; kt < 3; ++kt) {
            if (kt == 2 && wid == 0) continue;   // sample1 cols: zero for wave0
            if (kt == 0 && wid == 2) continue;   // sample0 cols: zero for wave2
            f16x8 bf[6];
#pragma unroll
            for (int nt = 0; nt < 6; ++nt)
                bf[nt] = *(const f16x8*)(PQt + (nt * 16 + l15) * 104 + kt * 32 + quad * 8);
#pragma unroll
            for (int nt = 0; nt < 6; ++nt)
                acc2[nt] = __builtin_amdgcn_mfma_f32_16x16x32_f16(mf[kt], bf[nt], acc2[nt], 0, 0, 0);
        }
        __builtin_amdgcn_s_setprio(0);

        const int so = (s - 24) * 576;

        // ---- d1 gates: 4 elements, 2 DPP exchanges each ----
#pragma unroll
        for (int rr = 0; rr < 4; ++rr) {
            float pf_s = xor8(lo ? acc2[2][rr] : acc2[1][rr]);
            float po_s = xor8(lo ? acc2[5][rr] : acc2[4][rr]);
            float iw1 = iwR1[rr], iw2 = iwR2[rr];
            int row = rowR[rr];
            float c = c1[rr];
            float pi = fmaf(iw1, acc2[0][rr], bC1[0]);
            float pf = fmaf(iw1, pf_s, bC1[1]);
            float pcs = fmaf(iw2, acc2[3][rr], bC1[2]);
            float po = fmaf(iw1, po_s, bC1[3]);
            float iv = sigm2(fmaf(wv1[0], c, pi));
            float fv = sigm2(fmaf(wv1[1], c, pf));
            float cn = fmaf(fv, c, iv * tanh2s(pcs));
            float ov = sigm2(fmaf(wv1[2], cn, po));
            c1[rr] = cn;
            float hv = ov * tanhc(cn);
            unsigned int pk = pkrtz(ov, hv);         // [ov, hv] f16 pair
            UO32[row * 36 + d1] = pk;                // k=2*d1, 2*d1+1
            if (s >= 24) seqh[sb[rr] + (unsigned int)(so + d1)] = (unsigned short)pk;
        }
        // ---- d2 gates: 2 elements, 2 DPP exchanges each, zero waste ----
#pragma unroll
        for (int e = 0; e < 2; ++e) {
            float sA = xor8(lo ? acc2[1][e + 2] : acc2[2][e]);
            float sB = xor8(lo ? acc2[4][e + 2] : acc2[5][e]);
            float g0 = lo ? acc2[1][e] : sA;           // i
            float g1 = lo ? sA : acc2[2][e + 2];       // f
            float g2 = lo ? acc2[4][e] : sB;           // c
            float g3 = lo ? sB : acc2[5][e + 2];       // o
            float iw1 = iw2v1[e], iw2 = iw2v2[e];
            int row = row2v[e];
            float c = c2[e];
            float pi = fmaf(iw1, g0, bC2[0]);
            float pf = fmaf(iw1, g1, bC2[1]);
            float pcs = fmaf(iw2, g2, bC2[2]);
            float po = fmaf(iw1, g3, bC2[3]);
            float iv = sigm2(fmaf(wv2[0], c, pi));
            float fv = sigm2(fmaf(wv2[1], c, pf));
            float cn = fmaf(fv, c, iv * tanh2s(pcs));
            float ov = sigm2(fmaf(wv2[2], cn, po));
            c2[e] = cn;
            float hv = ov * tanhc(cn);
            unsigned int pk = pkrtz(ov, hv);
            UO32[row * 36 + d2] = pk;
            if (s >= 24) seqh[sb2v[e] + (unsigned int)(so + d2)] = (unsigned short)pk;
        }
        BAR();   // (B) UO updated; PQt reads done
    }

    // ======== FUSE: projection tail (proj's LDS-staged pattern, run once) =====
    if (FUSE) {
        // all seqh stores for our 2 samples drained; LDS below is dead -> reuse
        asm volatile("s_waitcnt vmcnt(0) lgkmcnt(0)" ::: "memory");
        __builtin_amdgcn_s_barrier();
        unsigned short* SQ = (unsigned short*)smem;            // [48][104] =  9,984 B
        unsigned short* WH = (unsigned short*)(smem + 9984);   // [80][104] = 16,640 B

        f32x4 pacc[5];
#pragma unroll
        for (int j = 0; j < 5; ++j) pacc[j] = (f32x4)0.f;

        for (int kc = 0; kc < 576; kc += 96) {
            for (int i = tid; i < 576; i += TPB) {             // 48 rows x 12 chunks
                int rl = i / 12, c8 = i - rl * 12;
                int bl = rl / 24, t = rl - bl * 24;
                *(s16x8*)(&SQ[rl * 104 + c8 * 8]) =
                    *(const s16x8*)(seqh + (size_t)(b0 + bl) * 13824
                                          + (size_t)t * 576 + (size_t)(kc + c8 * 8));
            }
            for (int i = tid; i < 960; i += TPB) {             // 80 rows x 12 chunks
                int n = i / 12, c8 = i - n * 12;
                *(s16x8*)(&WH[n * 104 + c8 * 8]) =
                    *(const s16x8*)(WdH + (size_t)n * 576 + (size_t)(kc + c8 * 8));
            }
            BAR();
            __builtin_amdgcn_s_setprio(1);
#pragma unroll
            for (int kt = 0; kt < 3; ++kt) {
                int koff = kt * 32 + quad * 8;
                f16x8 a = *(const f16x8*)(&SQ[(wid * 16 + l15) * 104 + koff]);
#pragma unroll
                for (int j = 0; j < 5; ++j) {
                    f16x8 b = *(const f16x8*)(&WH[(j * 16 + l15) * 104 + koff]);
                    pacc[j] = __builtin_amdgcn_mfma_f32_16x16x32_f16(a, b, pacc[j], 0, 0, 0);
                }
            }
            __builtin_amdgcn_s_setprio(0);
            BAR();
        }
#pragma unroll
        for (int j = 0; j < 5; ++j) {
            int n = j * 16 + l15;
            if (n < 72) {
                float bv = bd[n];
#pragma unroll
                for (int r = 0; r < 4; ++r) {
                    int rl = wid * 16 + quad * 4 + r;
                    int bl = rl / 24, t = rl - bl * 24;
                    out[(size_t)(b0 + bl) * 1728 + (size_t)(t * 72 + n)] = pacc[j][r] + bv;
                }
            }
        }
    }
}

// Kernel 0: Wd (72x576 fp32) -> WdH (80x576 f16, rows 72-79 zero)
extern "C" __global__ void __launch_bounds__(256)
wd_conv(const float* __restrict__ Wd, unsigned short* __restrict__ WdH)
{
    int i = blockIdx.x * 256 + threadIdx.x;
    if (i < 46080) {
        int n = i / 576, k = i - n * 576;
        WdH[i] = (n < 72) ? f2h(Wd[n * 576 + k]) : (unsigned short)0;
    }
}

// Fallback projection (!preconv): legacy LDS path, inline Wd conversion.
__global__ void __launch_bounds__(256, 6)
gclstm_proj_lds(const unsigned short* __restrict__ seqh,
                const float* __restrict__ Wd,
                const float* __restrict__ bd,
                float* __restrict__ out)
{
    __shared__ unsigned short SQ[32 * 104];
    __shared__ unsigned short WH[80 * 104];

    const int tid = threadIdx.x;
    const int R0 = blockIdx.x * 32;
    const int lane = tid & 63, wid = tid >> 6;
    const int l15 = lane & 15, quad = lane >> 4;
    const int rt = wid & 1;
    const int c0 = (wid < 2) ? 0 : 3;
    const int nct = (wid < 2) ? 3 : 2;

    f32x4 acc[3];
#pragma unroll
    for (int j = 0; j < 3; ++j) acc[j] = (f32x4)0.f;

    for (int kc = 0; kc < 576; kc += 96) {
        __syncthreads();
        for (int i = tid; i < 384; i += 256) {
            int r = i / 12, c8 = i - r * 12;
            *(s16x8*)(&SQ[r * 104 + c8 * 8]) =
                *(const s16x8*)(seqh + (size_t)(R0 + r) * 576 + (size_t)(kc + c8 * 8));
        }
        for (int i = tid; i < 7680; i += 256) {
            int n = i / 96, kk = i - n * 96;
            float v = (n < 72) ? Wd[(size_t)n * 576 + (size_t)(kc + kk)] : 0.f;
            WH[n * 104 + kk] = f2h(v);
        }
        __syncthreads();
#pragma unroll
        for (int kt = 0; kt < 3; ++kt) {
            int koff = kt * 32 + quad * 8;
            f16x8 a = *(const f16x8*)(&SQ[(rt * 16 + l15) * 104 + koff]);
#pragma unroll
            for (int j = 0; j < 3; ++j) {
                if (j < nct) {
                    f16x8 b = *(const f16x8*)(&WH[((c0 + j) * 16 + l15) * 104 + koff]);
                    acc[j] = __builtin_amdgcn_mfma_f32_16x16x32_f16(a, b, acc[j], 0, 0, 0);
                }
            }
        }
    }

#pragma unroll
    for (int j = 0; j < 3; ++j) {
        if (j < nct) {
            int n = (c0 + j) * 16 + l15;
            if (n < 72) {
                float bv = bd[n];
                int rbase = R0 + rt * 16 + quad * 4;
#pragma unroll
                for (int r = 0; r < 4; ++r)
                    out[(size_t)(rbase + r) * 72 + (size_t)n] = acc[j][r] + bv;
            }
        }
    }
}

extern "C" void kernel_launch(void* const* d_in, const int* in_sizes, int n_in,
                              void* d_out, int out_size, void* d_ws, size_t ws_size,
                              hipStream_t stream)
{
    const float* src = (const float*)d_in[0];
    const float* tgt = (const float*)d_in[1];
    const float* We  = (const float*)d_in[2];
    const float* be  = (const float*)d_in[3];
    const float* Wxl = (const float*)d_in[4];
    const float* bxl = (const float*)d_in[5];
    const float* Wxr = (const float*)d_in[6];
    const float* Whl = (const float*)d_in[7];
    const float* bhl = (const float*)d_in[8];
    const float* Whr = (const float*)d_in[9];
    const float* wg  = (const float*)d_in[10];
    const float* bg  = (const float*)d_in[11];
    const float* Wd  = (const float*)d_in[12];
    const float* bd  = (const float*)d_in[13];
    float* out = (float*)d_out;                     // [2048][24][72] fp32
    unsigned short* seqh = (unsigned short*)d_ws;   // [2048][24][576] f16

    const size_t seq_bytes = (size_t)2048 * 24 * 576 * 2;
    unsigned short* WdH = (unsigned short*)((char*)d_ws + seq_bytes);
    const bool preconv = ws_size >= seq_bytes + (size_t)80 * 576 * 2;

    if (preconv) {
        wd_conv<<<dim3(180), dim3(256), 0, stream>>>(Wd, WdH);
        gclstm_main<1><<<dim3(1024), dim3(TPB), 0, stream>>>(
            src, tgt, We, be, Wxl, bxl, Wxr, Whl, bhl, Whr, wg, bg,
            seqh, WdH, bd, out);
    } else {
        gclstm_main<0><<<dim3(1024), dim3(TPB), 0, stream>>>(
            src, tgt, We, be, Wxl, bxl, Wxr, Whl, bhl, Whr, wg, bg,
            seqh, nullptr, bd, out);
        gclstm_proj_lds<<<dim3(1536), dim3(256), 0, stream>>>(seqh, Wd, bd, out);
    }
}

// Round 15
// 304.768 us; speedup vs baseline: 1.0467x; 1.0467x over previous
//
#include <hip/hip_runtime.h>

// GC-LSTM (SMPL) — fp32 I/O. Round 22: round 20 (303.9 us; main 229) + balanced
// phase-2 via row/column permutation of M'. Round 21's tail fusion REVERTED
// (regressed: main +20 us, gap only -5 -> gap is fixed harness overhead).
// Permutation: rows wave0=s0 j0-15, wave1=s1 j0-15, wave2=s0 j16-23 + s1 j16-23.
// Columns (quad-granular slots, kt=slot/8):
//   kt0: s0diag q0-3 (slots 0-3), s1adj q0-2 (4-6), s1diag q0 (7)
//   kt1: s0adj q0-5 (8-13), s0diag q4-5 (14-15)
//   kt2: s1adj q3-5 (16-18), s1diag q1-5 (19-23)
// -> wave0 uses kt0+kt1, wave1 kt0+kt2, wave2 kt1+kt2: 12 MFMA each (was
// 12/18/12; both barriers waited on wave1's 18). Same math, entries relocated.

typedef short  s16x8 __attribute__((ext_vector_type(8)));
typedef float  f32x4 __attribute__((ext_vector_type(4)));
typedef _Float16 f16x8 __attribute__((ext_vector_type(8)));

#define TPB 192
#define NB 2
#define PQ_OFF 0        // ushort[96][104] = 19,968 : PQt[n][j'] f16 (permuted j')
#define UO_OFF 19968    // ushort[48][72]  =  6,912 : k=2d X | 2d+1 h (d<24), 48-63 zero
#define SMEM_SZ 26880

#define BAR() do { asm volatile("s_waitcnt lgkmcnt(0)" ::: "memory"); \
                   __builtin_amdgcn_s_barrier(); } while (0)

#define L2E  1.4426950408889634f
#define L2E2 2.8853900817779268f

__device__ __forceinline__ unsigned short f2h(float f) {
    _Float16 h = (_Float16)f;            // RNE scalar convert (init paths)
    return *(unsigned short*)&h;
}
// hardware packed f32x2 -> f16x2 (RTZ), low = a, high = b : 1 VALU inst
__device__ __forceinline__ unsigned int pkrtz(float a, float b) {
    auto h = __builtin_amdgcn_cvt_pkrtz(a, b);   // __fp16 ext_vector_type(2)
    return *(unsigned int*)&h;
}
__device__ __forceinline__ float frcp(float x) { return __builtin_amdgcn_rcpf(x); }

#if __has_builtin(__builtin_amdgcn_exp2f)
#define EXP2(x) __builtin_amdgcn_exp2f(x)
#else
#define EXP2(x) __expf((x) * 0.6931471805599453f)
#endif

// sigmoid with PRE-SCALED argument y = log2e * x : 1/(1+2^-y)
__device__ __forceinline__ float sigm2(float y) {
    float t = EXP2(-y);
    return frcp(1.0f + t);
}
// tanh with PRE-SCALED argument ys = 2*log2e * x : (1-2^-ys)/(1+2^-ys)
__device__ __forceinline__ float tanh2s(float ys) {
    float t = EXP2(fminf(-ys, 86.64f));
    return (1.f - t) * frcp(1.f + t);
}
// tanh of a TRUE-scale value (cell state)
__device__ __forceinline__ float tanhc(float x) {
    float t = EXP2(fminf(x * -L2E2, 86.64f));
    return (1.f - t) * frcp(1.f + t);
}

// lane^8 exchange (within 16-lane rows) — DPP row_ror:8 if available
#if __has_builtin(__builtin_amdgcn_mov_dpp)
__device__ __forceinline__ float xor8(float v) {
    int r = __builtin_amdgcn_mov_dpp(__float_as_int(v), 0x128, 0xf, 0xf, false);
    return __int_as_float(r);
}
#else
__device__ __forceinline__ float xor8(float v) { return __shfl_xor(v, 8); }
#endif

extern "C" __global__ void __launch_bounds__(TPB, 3)
gclstm_main(const float* __restrict__ src,
            const float* __restrict__ tgt,
            const float* __restrict__ We,
            const float* __restrict__ be,
            const float* __restrict__ Wxl,
            const float* __restrict__ bxl,
            const float* __restrict__ Wxr,
            const float* __restrict__ Whl,
            const float* __restrict__ bhl,
            const float* __restrict__ Whr,
            const float* __restrict__ wg,
            const float* __restrict__ bg,
            unsigned short* __restrict__ seqh)
{
    __shared__ __align__(16) char smem[SMEM_SZ];
    unsigned short* PQt  = (unsigned short*)(smem + PQ_OFF);
    unsigned short* UO   = (unsigned short*)(smem + UO_OFF);
    unsigned int*   UO32 = (unsigned int*)(smem + UO_OFF);

    const int tid = threadIdx.x;
    const int b0 = blockIdx.x * NB;
    const int lane = tid & 63, wid = tid >> 6;      // 3 waves
    const int l15 = lane & 15, quad = lane >> 4;

    const int par[24] = {-1,0,0,0,1,2,3,4,5,6,7,8,9,9,9,12,13,14,16,17,18,19,20,21};
    // column-quad permutation: QP[sample][path][q] = slot (kt = slot/8)
    const int QP[2][2][6] = {
        { {8,9,10,11,12,13}, {0,1,2,3,14,15} },
        { {4,5,6,16,17,18},  {7,19,20,21,22,23} }
    };
    // inverse: slot -> (sample, path, q)
    const int IS[24] = {0,0,0,0, 1,1,1,1, 0,0,0,0,0,0,0,0, 1,1,1,1,1,1,1,1};
    const int IP[24] = {1,1,1,1, 0,0,0,1, 0,0,0,0,0,0,1,1, 0,0,0,1,1,1,1,1};
    const int IQ[24] = {0,1,2,3, 0,1,2,0, 0,1,2,3,4,5,4,5, 3,4,5,1,2,3,4,5};

    // ---- stage-1 weight fragments in registers: wave wid owns col-tiles 4w..4w+3
    // k interleaved: k=2d -> X-feature d (Wx), k=2d+1 -> h-feature d (Wh); k>=48 zero
    f16x8 w1f[4][2];
#pragma unroll
    for (int cj = 0; cj < 4; ++cj) {
        int np = (wid * 4 + cj) * 16 + l15;
        int path = np >= 96 ? 1 : 0;
        int nn = np - path * 96;
        int g = nn / 24, d = nn - g * 24;
        const float* Wx = path ? Wxr : Wxl;
        const float* Wh = path ? Whr : Whl;
#pragma unroll
        for (int kt = 0; kt < 2; ++kt) {
            f16x8 f;
#pragma unroll
            for (int kk = 0; kk < 8; ++kk) {
                int k = kt * 32 + quad * 8 + kk;
                float v = 0.f;
                if (k < 48) {
                    int df = k >> 1;
                    v = (k & 1) ? Wh[g * 576 + d * 24 + df] : Wx[g * 576 + d * 24 + df];
                }
                f[kk] = (_Float16)v;
            }
            w1f[cj][kt] = f;
        }
    }

    // ---- pack column table: colT[rt][cj] = PQt col for (storage jg, path) ----
    int colT[3][4];
#pragma unroll
    for (int rt = 0; rt < 3; ++rt)
#pragma unroll
        for (int cj = 0; cj < 4; ++cj) {
            int np = (wid * 4 + cj) * 16 + l15;
            int path = np >= 96 ? 1 : 0;
            int jg = rt * 16 + quad * 4;
            int sm = jg >= 24 ? 1 : 0;
            int jm = jg - sm * 24;
            colT[rt][cj] = QP[sm][path][jm >> 2] * 4;
        }

    // ---- permuted row mapping for this wave (logical row l within wave tile):
    //      wave0: s0 j(l); wave1: s1 j(l); wave2: l<8 -> s0 j16+l, else s1 j16+(l-8)
    // ---- M' fragments: built from permuted columns, only 2 kt used per wave
    f16x8 mf[3];
    {
        int rs = (wid == 0) ? 0 : (wid == 1) ? 1 : (l15 < 8 ? 0 : 1);
        int rj = (wid < 2) ? l15 : 16 + (l15 & 7);
        int cnt = 1 + (par[rj] >= 0 ? 1 : 0);
#pragma unroll
        for (int ch = 0; ch < 24; ++ch) cnt += (par[ch] == rj) ? 1 : 0;
        float cntf = (float)cnt;
#pragma unroll
        for (int kt = 0; kt < 3; ++kt) {
            f16x8 f;
#pragma unroll
            for (int kk = 0; kk < 8; ++kk) {
                int jp = kt * 32 + quad * 8 + kk;
                int slot = jp >> 2, pos = jp & 3;
                int j = IQ[slot] * 4 + pos;
                float v = 0.f;
                if (IS[slot] == rs) {
                    if (IP[slot] == 0)
                        v = (j == rj || par[j] == rj || par[rj] == j) ? 1.f : 0.f;
                    else
                        v = (j == rj) ? cntf : 0.f;
                }
                f[kk] = (_Float16)v;
            }
            mf[kt] = f;
        }
    }

    // ---- per-lane gate constants: d1 = l15, d2 = 16+(l15&7)
    // PRE-SCALED: i/f/o-gate consts x log2e (sigm2); c-gate consts x 2*log2e (tanh2s)
    const int d1 = l15;
    const int d2 = 16 + (l15 & 7);
    const bool lo = l15 < 8;
    float bC1[4], bC2[4], wv1[3], wv2[3];
#pragma unroll
    for (int g = 0; g < 4; ++g) {
        float sc = (g == 2) ? L2E2 : L2E;
        bC1[g] = (bxl[g * 24 + d1] + bhl[g * 24 + d1] + bg[g * 24 + d1]) * sc;
        bC2[g] = (bxl[g * 24 + d2] + bhl[g * 24 + d2] + bg[g * 24 + d2]) * sc;
    }
#pragma unroll
    for (int p = 0; p < 3; ++p) {
        wv1[p] = wg[p * 24 + d1] * L2E;
        wv2[p] = wg[p * 24 + d2] * L2E;
    }

    // ---- gate row tables (PERMUTED rows; li = quad*4+rr = C-layout row) ----
    int rowR[4];
    float iwR1[4], iwR2[4];
    unsigned int sb[4];
#pragma unroll
    for (int rr = 0; rr < 4; ++rr) {
        int li = quad * 4 + rr;
        int sm = (wid == 0) ? 0 : (wid == 1) ? 1 : (li < 8 ? 0 : 1);
        int j = (wid < 2) ? li : 16 + (li & 7);
        rowR[rr] = sm * 24 + j;                       // storage row in UO
        int cnt = 1 + (par[j] >= 0 ? 1 : 0);
#pragma unroll
        for (int ch = 0; ch < 24; ++ch) cnt += (par[ch] == j) ? 1 : 0;
        float iw = cnt == 2 ? 0.5f : cnt == 3 ? (1.f / 3.f) : cnt == 4 ? 0.25f : 0.2f;
        iwR1[rr] = iw * L2E;
        iwR2[rr] = iw * L2E2;
        sb[rr] = (unsigned int)((b0 + sm) * 13824 + j * 24);
    }
    // d2 element constants (element e active on rr = lo ? e : e+2)
    int row2v[2]; float iw2v1[2], iw2v2[2]; unsigned int sb2v[2];
#pragma unroll
    for (int e = 0; e < 2; ++e) {
        int rsel = lo ? e : e + 2;
        row2v[e] = rowR[rsel];
        iw2v1[e] = iwR1[rsel]; iw2v2[e] = iwR2[rsel];
        sb2v[e] = sb[rsel];
    }

    float c1[4] = {0.f, 0.f, 0.f, 0.f};
    float c2[2] = {0.f, 0.f};

    // ---- encoder init: X at even k, h=0 at odd k; pad k 48..63 zeroed ----
#pragma unroll
    for (int t = 0; t < 3; ++t) {
        int task = tid + t * TPB;
        int row = task / 12, dp = task - row * 12;
        int b = b0 + row / 24, j = row % 24;
        const float* sp = src + (size_t)b * 1728 + j * 3;
        float s0 = sp[0], s1 = sp[1], s2 = sp[2];
        int d = 2 * dp;
        float x0 = be[d] + s0 * We[d * 3] + s1 * We[d * 3 + 1] + s2 * We[d * 3 + 2];
        float x1 = be[d + 1] + s0 * We[d * 3 + 3] + s1 * We[d * 3 + 4] + s2 * We[d * 3 + 5];
        x0 = fmaxf(x0, 0.f); x1 = fmaxf(x1, 0.f);
        uint2 wv; wv.x = pkrtz(x0, 0.f); wv.y = pkrtz(x1, 0.f);
        *(uint2*)(UO32 + row * 36 + 2 * dp) = wv;   // shorts [x0,0,x1,0]
    }
    {   // zero pad k=48..63 for all 48 rows (192 threads x 1 uint2 exactly)
        int row = tid >> 2, c = tid & 3;
        uint2 z; z.x = 0u; z.y = 0u;
        *(uint2*)(UO32 + row * 36 + 24 + 2 * c) = z;
    }
    __syncthreads();

    for (int s = 0; s < 48; ++s) {
        if (s == 24) {
            // decode inject: X = relu(enc(tgt[:,0])) at even k only; h preserved
#pragma unroll
            for (int t = 0; t < 3; ++t) {
                int task = tid + t * TPB;
                int row = task / 12, dp = task - row * 12;
                int b = b0 + row / 24, j = row % 24;
                const float* tp = tgt + (size_t)b * 1728 + j * 3;
                float s0 = tp[0], s1 = tp[1], s2 = tp[2];
                int d = 2 * dp;
                float x0 = be[d] + s0 * We[d * 3] + s1 * We[d * 3 + 1] + s2 * We[d * 3 + 2];
                float x1 = be[d + 1] + s0 * We[d * 3 + 3] + s1 * We[d * 3 + 4]
                         + s2 * We[d * 3 + 5];
                x0 = fmaxf(x0, 0.f); x1 = fmaxf(x1, 0.f);
                UO[row * 72 + 4 * dp] = f2h(x0);
                UO[row * 72 + 4 * dp + 2] = f2h(x1);
            }
            BAR();
        }

        // ---- phase 1: stage-1 MFMA (read UO) + pack -> PQt (permuted cols) ----
        f32x4 acc1[3][4];
#pragma unroll
        for (int rt = 0; rt < 3; ++rt)
#pragma unroll
            for (int cj = 0; cj < 4; ++cj) acc1[rt][cj] = (f32x4)0.f;
        __builtin_amdgcn_s_setprio(1);
#pragma unroll
        for (int kt = 0; kt < 2; ++kt) {
            f16x8 a[3];
#pragma unroll
            for (int rt = 0; rt < 3; ++rt)
                a[rt] = *(const f16x8*)(UO + (rt * 16 + l15) * 72 + kt * 32 + quad * 8);
#pragma unroll
            for (int rt = 0; rt < 3; ++rt)
#pragma unroll
                for (int cj = 0; cj < 4; ++cj)
                    acc1[rt][cj] = __builtin_amdgcn_mfma_f32_16x16x32_f16(a[rt], w1f[cj][kt], acc1[rt][cj], 0, 0, 0);
        }
        __builtin_amdgcn_s_setprio(0);
#pragma unroll
        for (int rt = 0; rt < 3; ++rt)
#pragma unroll
            for (int cj = 0; cj < 4; ++cj) {
                int np = (wid * 4 + cj) * 16 + l15;
                int nn = np - (np >= 96 ? 96 : 0);
                uint2 wv;
                wv.x = pkrtz(acc1[rt][cj][0], acc1[rt][cj][1]);
                wv.y = pkrtz(acc1[rt][cj][2], acc1[rt][cj][3]);
                *(uint2*)(PQt + nn * 104 + colT[rt][cj]) = wv;
            }
        BAR();   // (A) PQt ready; UO reads done

        // ---- phase 2: stage-2 MFMA; balanced: every wave exactly 2 kt ----
        f32x4 acc2[6];
#pragma unroll
        for (int nt = 0; nt < 6; ++nt) acc2[nt] = (f32x4)0.f;
        __builtin_amdgcn_s_setprio(1);
#pragma unroll
        for (int kt = 0; kt < 3; ++kt) {
            if (kt == 2 && wid == 0) continue;   // wave0: kt0+kt1
            if (kt == 1 && wid == 1) continue;   // wave1: kt0+kt2
            if (kt == 0 && wid == 2) continue;   // wave2: kt1+kt2
            f16x8 bf[6];
#pragma unroll
            for (int nt = 0; nt < 6; ++nt)
                bf[nt] = *(const f16x8*)(PQt + (nt * 16 + l15) * 104 + kt * 32 + quad * 8);
#pragma unroll
            for (int nt = 0; nt < 6; ++nt)
                acc2[nt] = __builtin_amdgcn_mfma_f32_16x16x32_f16(mf[kt], bf[nt], acc2[nt], 0, 0, 0);
        }
        __builtin_amdgcn_s_setprio(0);

        const int so = (s - 24) * 576;

        // ---- d1 gates: 4 elements, 2 DPP exchanges each ----
#pragma unroll
        for (int rr = 0; rr < 4; ++rr) {
            float pf_s = xor8(lo ? acc2[2][rr] : acc2[1][rr]);
            float po_s = xor8(lo ? acc2[5][rr] : acc2[4][rr]);
            float iw1 = iwR1[rr], iw2 = iwR2[rr];
            int row = rowR[rr];
            float c = c1[rr];
            float pi = fmaf(iw1, acc2[0][rr], bC1[0]);
            float pf = fmaf(iw1, pf_s, bC1[1]);
            float pcs = fmaf(iw2, acc2[3][rr], bC1[2]);
            float po = fmaf(iw1, po_s, bC1[3]);
            float iv = sigm2(fmaf(wv1[0], c, pi));
            float fv = sigm2(fmaf(wv1[1], c, pf));
            float cn = fmaf(fv, c, iv * tanh2s(pcs));
            float ov = sigm2(fmaf(wv1[2], cn, po));
            c1[rr] = cn;
            float hv = ov * tanhc(cn);
            unsigned int pk = pkrtz(ov, hv);         // [ov, hv] f16 pair
            UO32[row * 36 + d1] = pk;                // k=2*d1, 2*d1+1
            if (s >= 24) seqh[sb[rr] + (unsigned int)(so + d1)] = (unsigned short)pk;
        }
        // ---- d2 gates: 2 elements, 2 DPP exchanges each, zero waste ----
#pragma unroll
        for (int e = 0; e < 2; ++e) {
            float sA = xor8(lo ? acc2[1][e + 2] : acc2[2][e]);
            float sB = xor8(lo ? acc2[4][e + 2] : acc2[5][e]);
            float g0 = lo ? acc2[1][e] : sA;           // i
            float g1 = lo ? sA : acc2[2][e + 2];       // f
            float g2 = lo ? acc2[4][e] : sB;           // c
            float g3 = lo ? sB : acc2[5][e + 2];       // o
            float iw1 = iw2v1[e], iw2 = iw2v2[e];
            int row = row2v[e];
            float c = c2[e];
            float pi = fmaf(iw1, g0, bC2[0]);
            float pf = fmaf(iw1, g1, bC2[1]);
            float pcs = fmaf(iw2, g2, bC2[2]);
            float po = fmaf(iw1, g3, bC2[3]);
            float iv = sigm2(fmaf(wv2[0], c, pi));
            float fv = sigm2(fmaf(wv2[1], c, pf));
            float cn = fmaf(fv, c, iv * tanh2s(pcs));
            float ov = sigm2(fmaf(wv2[2], cn, po));
            c2[e] = cn;
            float hv = ov * tanhc(cn);
            unsigned int pk = pkrtz(ov, hv);
            UO32[row * 36 + d2] = pk;
            if (s >= 24) seqh[sb2v[e] + (unsigned int)(so + d2)] = (unsigned short)pk;
        }
        BAR();   // (B) UO updated; PQt reads done
    }
}

// Kernel 0: Wd (72x576 fp32) -> WdH (80x576 f16, rows 72-79 zero)
extern "C" __global__ void __launch_bounds__(256)
wd_conv(const float* __restrict__ Wd, unsigned short* __restrict__ WdH)
{
    int i = blockIdx.x * 256 + threadIdx.x;
    if (i < 46080) {
        int n = i / 576, k = i - n * 576;
        WdH[i] = (n < 72) ? f2h(Wd[n * 576 + k]) : (unsigned short)0;
    }
}

// Kernel 2: out[row][o] = bd[o] + sum_k seq[row][k]*Wd[o][k]; f16 MFMA.
// 1536 blocks x 256 thr, 32 rows/block, 6 blocks/CU. Wave w: row-tile w&1,
// col-tiles {0,1,2} (w<2) or {3,4} (w>=2). Reg-staged prefetch + raw barriers.
template <int PRECONV>
__global__ void __launch_bounds__(256, 6)
gclstm_proj(const unsigned short* __restrict__ seqh,
            const unsigned short* __restrict__ WdH,
            const float* __restrict__ Wd,
            const float* __restrict__ bd,
            float* __restrict__ out)
{
    __shared__ unsigned short SQ[32 * 104];   //  6,656 B
    __shared__ unsigned short WH[80 * 104];   // 16,640 B

    const int tid = threadIdx.x;
    const int R0 = blockIdx.x * 32;
    const int lane = tid & 63, wid = tid >> 6;
    const int l15 = lane & 15, quad = lane >> 4;
    const int rt = wid & 1;
    const int c0 = (wid < 2) ? 0 : 3;
    const int nct = (wid < 2) ? 3 : 2;

    f32x4 acc[3];
#pragma unroll
    for (int j = 0; j < 3; ++j) acc[j] = (f32x4)0.f;

    if (PRECONV) {
        s16x8 sreg[2], wreg[4];
        const int r0s = tid / 12, c0s = tid - r0s * 12;
        const int i1 = tid + 256;
        const int r1s = i1 / 12, c1s = i1 - r1s * 12;
        // prologue: issue chunk 0
        sreg[0] = *(const s16x8*)(seqh + (size_t)(R0 + r0s) * 576 + (size_t)(c0s * 8));
        if (tid < 128)
            sreg[1] = *(const s16x8*)(seqh + (size_t)(R0 + r1s) * 576 + (size_t)(c1s * 8));
#pragma unroll
        for (int j = 0; j < 4; ++j) {
            int i = tid + j * 256;
            if (i < 960) { int n = i / 12, c8 = i - n * 12;
                wreg[j] = *(const s16x8*)(WdH + (size_t)n * 576 + (size_t)(c8 * 8)); }
        }
        for (int kc = 0; kc < 576; kc += 96) {
            // commit staged regs -> LDS (vmcnt waits inserted at reg use)
            *(s16x8*)(&SQ[r0s * 104 + c0s * 8]) = sreg[0];
            if (tid < 128) *(s16x8*)(&SQ[r1s * 104 + c1s * 8]) = sreg[1];
#pragma unroll
            for (int j = 0; j < 4; ++j) {
                int i = tid + j * 256;
                if (i < 960) { int n = i / 12, c8 = i - n * 12;
                    *(s16x8*)(&WH[n * 104 + c8 * 8]) = wreg[j]; }
            }
            BAR();
            if (kc + 96 < 576) {    // issue next chunk; flies across barrier + MFMA
                sreg[0] = *(const s16x8*)(seqh + (size_t)(R0 + r0s) * 576 + (size_t)(kc + 96 + c0s * 8));
                if (tid < 128)
                    sreg[1] = *(const s16x8*)(seqh + (size_t)(R0 + r1s) * 576 + (size_t)(kc + 96 + c1s * 8));
#pragma unroll
                for (int j = 0; j < 4; ++j) {
                    int i = tid + j * 256;
                    if (i < 960) { int n = i / 12, c8 = i - n * 12;
                        wreg[j] = *(const s16x8*)(WdH + (size_t)n * 576 + (size_t)(kc + 96 + c8 * 8)); }
                }
            }
#pragma unroll
            for (int kt = 0; kt < 3; ++kt) {
                int koff = kt * 32 + quad * 8;
                f16x8 a = *(const f16x8*)(&SQ[(rt * 16 + l15) * 104 + koff]);
#pragma unroll
                for (int j = 0; j < 3; ++j) {
                    if (j < nct) {
                        f16x8 b = *(const f16x8*)(&WH[((c0 + j) * 16 + l15) * 104 + koff]);
                        acc[j] = __builtin_amdgcn_mfma_f32_16x16x32_f16(a, b, acc[j], 0, 0, 0);
                    }
                }
            }
            BAR();   // LDS reads done before next commit
        }
    } else {
        for (int kc = 0; kc < 576; kc += 96) {
            __syncthreads();
            for (int i = tid; i < 384; i += 256) {
                int r = i / 12, c8 = i - r * 12;
                *(s16x8*)(&SQ[r * 104 + c8 * 8]) =
                    *(const s16x8*)(seqh + (size_t)(R0 + r) * 576 + (size_t)(kc + c8 * 8));
            }
            for (int i = tid; i < 7680; i += 256) {
                int n = i / 96, kk = i - n * 96;
                float v = (n < 72) ? Wd[(size_t)n * 576 + (size_t)(kc + kk)] : 0.f;
                WH[n * 104 + kk] = f2h(v);
            }
            __syncthreads();
#pragma unroll
            for (int kt = 0; kt < 3; ++kt) {
                int koff = kt * 32 + quad * 8;
                f16x8 a = *(const f16x8*)(&SQ[(rt * 16 + l15) * 104 + koff]);
#pragma unroll
                for (int j = 0; j < 3; ++j) {
                    if (j < nct) {
                        f16x8 b = *(const f16x8*)(&WH[((c0 + j) * 16 + l15) * 104 + koff]);
                        acc[j] = __builtin_amdgcn_mfma_f32_16x16x32_f16(a, b, acc[j], 0, 0, 0);
                    }
                }
            }
        }
    }

#pragma unroll
    for (int j = 0; j < 3; ++j) {
        if (j < nct) {
            int n = (c0 + j) * 16 + l15;
            if (n < 72) {
                float bv = bd[n];
                int rbase = R0 + rt * 16 + quad * 4;
#pragma unroll
                for (int r = 0; r < 4; ++r)
                    out[(size_t)(rbase + r) * 72 + (size_t)n] = acc[j][r] + bv;
            }
        }
    }
}

extern "C" void kernel_launch(void* const* d_in, const int* in_sizes, int n_in,
                              void* d_out, int out_size, void* d_ws, size_t ws_size,
                              hipStream_t stream)
{
    const float* src = (const float*)d_in[0];
    const float* tgt = (const float*)d_in[1];
    const float* We  = (const float*)d_in[2];
    const float* be  = (const float*)d_in[3];
    const float* Wxl = (const float*)d_in[4];
    const float* bxl = (const float*)d_in[5];
    const float* Wxr = (const float*)d_in[6];
    const float* Whl = (const float*)d_in[7];
    const float* bhl = (const float*)d_in[8];
    const float* Whr = (const float*)d_in[9];
    const float* wg  = (const float*)d_in[10];
    const float* bg  = (const float*)d_in[11];
    const float* Wd  = (const float*)d_in[12];
    const float* bd  = (const float*)d_in[13];
    float* out = (float*)d_out;                     // [2048][24][72] fp32
    unsigned short* seqh = (unsigned short*)d_ws;   // [2048][24][576] f16

    const size_t seq_bytes = (size_t)2048 * 24 * 576 * 2;
    unsigned short* WdH = (unsigned short*)((char*)d_ws + seq_bytes);
    const bool preconv = ws_size >= seq_bytes + (size_t)80 * 576 * 2;

    if (preconv)
        wd_conv<<<dim3(180), dim3(256), 0, stream>>>(Wd, WdH);
    gclstm_main<<<dim3(1024), dim3(TPB), 0, stream>>>(
        src, tgt, We, be, Wxl, bxl, Wxr, Whl, bhl, Whr, wg, bg, seqh);
    if (preconv)
        gclstm_proj<1><<<dim3(1536), dim3(256), 0, stream>>>(seqh, WdH, Wd, bd, out);
    else
        gclstm_proj<0><<<dim3(1536), dim3(256), 0, stream>>>(seqh, nullptr, Wd, bd, out);
}